// Round 3
// baseline (1518.158 us; speedup 1.0000x reference)
//
#include <hip/hip_runtime.h>
#include <hip/hip_bf16.h>

// RQ-VAE residual quantization, MI355X gfx950.
// data [65536][256] f32, codebooks [4][1024][256] f32.
// out = [zq_stack 4*65536*256][semantic_ids 65536*4 (as float)][loss 1], all f32.
//
// Single-pass bf16-MFMA scores with running-min candidate collection
// (superset of final margin set; chunk 0 peeled with register-buffered
// scores), fp64 exact rescore of candidates (atomicMin on packed score|code
// key, lowest-index tie-break), fused gather/update epilogue.
// 512-thread blocks: 8 waves = 4 row-tiles (32 rows, mi=2) x 2 code-halves.
// Residual r lives in the zq_stack[3] slot of d_out (read-before-write).

#define NROWS   65536
#define DIM     256
#define KCODES  1024
#define LEVELS  4
#define CH      (NROWS * DIM)
#define IDS_OFF (LEVELS * CH)

#define BM      128
#define NCHUNK  16
#define CAP     32
#define MARGIN  8.0f
#define CHUNK_USH 16384          // 64 codes * 256 bf16
#define LVL_USH   262144         // 1024 * 256

typedef __attribute__((ext_vector_type(8))) short bf16x8;
typedef __attribute__((ext_vector_type(4))) float f32x4;
typedef const __attribute__((address_space(1))) void* gp_t;
typedef __attribute__((address_space(3))) void* lp_t;

__device__ __forceinline__ unsigned short f2bf(float x) {
    __hip_bfloat16 h = __float2bfloat16(x);
    unsigned short r; __builtin_memcpy(&r, &h, 2); return r;
}
__device__ __forceinline__ float bf2f(unsigned short u) {
    __hip_bfloat16 h; __builtin_memcpy(&h, &u, 2); return __bfloat162float(h);
}

// ---- k_prep: frag-tiled bf16 codebook + fp32 sum(c_bf16^2) + fp64 sum(c^2) ----
// Layout (ushort idx): ((((L*16+chunk)*4+nt)*8+kk)*64 + (g*16+li))*8 + h
__global__ __launch_bounds__(64) void k_prep(const float* __restrict__ cb,
                                             unsigned short* __restrict__ cbw,
                                             float* __restrict__ cn2w,
                                             double* __restrict__ cn2d) {
    int cr = blockIdx.x;                 // level*1024 + code
    int L = cr >> 10, c = cr & 1023;
    int l = threadIdx.x;                 // handles floats l*4..l*4+3
    float4 v = *(const float4*)(cb + (size_t)cr * DIM + l * 4);
    ushort4 st;
    st.x = f2bf(v.x); st.y = f2bf(v.y); st.z = f2bf(v.z); st.w = f2bf(v.w);
    int b = l * 8;
    int kk = b >> 6, g = (b >> 4) & 3, h = (b & 15) >> 1;
    int idx = ((((L * 16 + (c >> 6)) * 4 + ((c >> 4) & 3)) * 8 + kk) * 64
               + (g * 16 + (c & 15))) * 8 + h;
    *(ushort4*)(cbw + idx) = st;
    float f0 = bf2f(st.x), f1 = bf2f(st.y), f2 = bf2f(st.z), f3 = bf2f(st.w);
    float sq = f0 * f0 + f1 * f1 + f2 * f2 + f3 * f3;
    double dq = (double)v.x * v.x + (double)v.y * v.y
              + (double)v.z * v.z + (double)v.w * v.w;
    #pragma unroll
    for (int m = 32; m; m >>= 1) {
        sq += __shfl_xor(sq, m);
        dq += __shfl_xor(dq, m);
    }
    if (l == 0) { cn2w[cr] = sq; cn2d[cr] = dq; }
}

// ---- k_score: single-pass approx scores + exact refine + update ----
__global__ __launch_bounds__(512, 4) void k_score(
    const float* rsrc,
    const float* __restrict__ cbf,
    const unsigned short* __restrict__ cbwL,
    const float* __restrict__ cn2L,
    const double* __restrict__ cn2dL,
    const float* zqprev, float* zqout, float* rnext,
    float* __restrict__ ids_out,
    double* __restrict__ blockpart,
    int level)
{
    __shared__ unsigned short cbuf[2 * CHUNK_USH];   // 64 KB double buffer
    __shared__ float cn2s[KCODES];                   // 4 KB
    __shared__ unsigned short cand[BM * CAP];        // 8 KB
    __shared__ int cnt[BM];
    __shared__ unsigned long long winkey[BM];
    __shared__ int winid[BM];
    __shared__ float wl[8];

    const int tid = threadIdx.x;
    const int w = tid >> 6, l = tid & 63;
    const int g = l >> 4, li = l & 15;
    const int wr = w & 3;                // row-tile pair (32 rows)
    const int h = w >> 2;                // code half: nt in {2h, 2h+1}
    const int rows0 = blockIdx.x * BM;

    // stage chunk T into buffer T&1 (linear DMA, 4 x 16B per thread)
    #define STAGE(T) do {                                                       \
        int _kc = (T) & 15, _bs = (T) & 1;                                      \
        const unsigned short* _g = cbwL + _kc * CHUNK_USH;                      \
        unsigned short* _d = &cbuf[_bs * CHUNK_USH];                            \
        _Pragma("unroll")                                                       \
        for (int _r = 0; _r < 4; ++_r)                                          \
            __builtin_amdgcn_global_load_lds((gp_t)(_g + _r * 4096 + tid * 8),  \
                                             (lp_t)(_d + _r * 4096 + tid * 8),  \
                                             16, 0, 0);                         \
    } while (0)

    STAGE(0);
    cn2s[tid] = cn2L[tid];
    cn2s[tid + 512] = cn2L[tid + 512];
    if (tid < BM) { cnt[tid] = 0; winkey[tid] = ~0ULL; }

    // A-fragments: 32 rows per wave in bf16 registers
    bf16x8 af[2][8];
    #pragma unroll
    for (int mi = 0; mi < 2; ++mi) {
        int row = rows0 + (2 * wr + mi) * 16 + li;
        const float* rp = rsrc + (size_t)row * DIM;
        #pragma unroll
        for (int kk = 0; kk < 8; ++kk) {
            int d0 = kk * 32 + 8 * g;
            float4 v0 = *(const float4*)(rp + d0);
            float4 v1 = *(const float4*)(rp + d0 + 4);
            bf16x8 t;
            t[0] = (short)f2bf(v0.x); t[1] = (short)f2bf(v0.y);
            t[2] = (short)f2bf(v0.z); t[3] = (short)f2bf(v0.w);
            t[4] = (short)f2bf(v1.x); t[5] = (short)f2bf(v1.y);
            t[6] = (short)f2bf(v1.z); t[7] = (short)f2bf(v1.w);
            af[mi][kk] = t;
        }
    }

    float minv[2][4], rowm[2][4], sv[2][4];
    #pragma unroll
    for (int mi = 0; mi < 2; ++mi)
        #pragma unroll
        for (int rg = 0; rg < 4; ++rg) minv[mi][rg] = 3.0e38f;

    // share running min across the 16 li-lanes per row, refresh thresholds
    #define SHARE_MINS() do {                                                   \
        _Pragma("unroll")                                                       \
        for (int mi = 0; mi < 2; ++mi)                                          \
            _Pragma("unroll")                                                   \
            for (int rg = 0; rg < 4; ++rg) {                                    \
                float v = minv[mi][rg];                                         \
                v = fminf(v, __shfl_xor(v, 1));                                 \
                v = fminf(v, __shfl_xor(v, 2));                                 \
                v = fminf(v, __shfl_xor(v, 4));                                 \
                v = fminf(v, __shfl_xor(v, 8));                                 \
                minv[mi][rg] = v; rowm[mi][rg] = v + MARGIN;                    \
            }                                                                   \
    } while (0)

    #define COLLECT(codebase) do {                                              \
        bool _any = false;                                                      \
        _Pragma("unroll")                                                       \
        for (int mi = 0; mi < 2; ++mi)                                          \
            _Pragma("unroll")                                                   \
            for (int rg = 0; rg < 4; ++rg)                                      \
                _any |= (sv[mi][rg] < rowm[mi][rg]);                            \
        if (__any(_any)) {                                                      \
            _Pragma("unroll")                                                   \
            for (int mi = 0; mi < 2; ++mi)                                      \
                _Pragma("unroll")                                               \
                for (int rg = 0; rg < 4; ++rg)                                  \
                    if (sv[mi][rg] < rowm[mi][rg]) {                            \
                        int _row = (2 * wr + mi) * 16 + 4 * g + rg;             \
                        int _slot = atomicAdd(&cnt[_row], 1);                   \
                        if (_slot < CAP)                                        \
                            cand[_row * CAP + _slot] =                          \
                                (unsigned short)((codebase) + li);              \
                    }                                                           \
        }                                                                       \
    } while (0)

    #define SCORE_NT(fb, kc, nt) do {                                           \
        f32x4 acc0 = {0.f, 0.f, 0.f, 0.f};                                      \
        f32x4 acc1 = {0.f, 0.f, 0.f, 0.f};                                      \
        const unsigned short* fp8 = (fb) + ((nt) * 8) * 512 + l * 8;            \
        _Pragma("unroll")                                                       \
        for (int kk = 0; kk < 8; ++kk) {                                        \
            bf16x8 bfr = *(const bf16x8*)(fp8 + kk * 512);                      \
            acc0 = __builtin_amdgcn_mfma_f32_16x16x32_bf16(af[0][kk], bfr, acc0, 0, 0, 0); \
            acc1 = __builtin_amdgcn_mfma_f32_16x16x32_bf16(af[1][kk], bfr, acc1, 0, 0, 0); \
        }                                                                       \
        float c2 = cn2s[(kc) * 64 + (nt) * 16 + li];                            \
        _Pragma("unroll")                                                       \
        for (int rg = 0; rg < 4; ++rg) {                                        \
            sv[0][rg] = __builtin_fmaf(-2.f, acc0[rg], c2);                     \
            sv[1][rg] = __builtin_fmaf(-2.f, acc1[rg], c2);                     \
            minv[0][rg] = fminf(minv[0][rg], sv[0][rg]);                        \
            minv[1][rg] = fminf(minv[1][rg], sv[1][rg]);                        \
        }                                                                       \
    } while (0)

    __syncthreads();                      // chunk 0 staged; cn2s/cnt ready

    // ---- chunk 0 (peeled): buffer scores, collect after min is known ----
    float s0[2][2][4];                    // [nt2][mi][rg]
    STAGE(1);
    {
        const unsigned short* fb = cbuf;
        #pragma unroll
        for (int nt2 = 0; nt2 < 2; ++nt2) {
            int nt = 2 * h + nt2;
            SCORE_NT(fb, 0, nt);
            #pragma unroll
            for (int mi = 0; mi < 2; ++mi)
                #pragma unroll
                for (int rg = 0; rg < 4; ++rg) s0[nt2][mi][rg] = sv[mi][rg];
        }
        SHARE_MINS();
        #pragma unroll
        for (int nt2 = 0; nt2 < 2; ++nt2) {
            #pragma unroll
            for (int mi = 0; mi < 2; ++mi)
                #pragma unroll
                for (int rg = 0; rg < 4; ++rg) sv[mi][rg] = s0[nt2][mi][rg];
            COLLECT((2 * h + nt2) * 16);
        }
    }
    __syncthreads();                      // chunk 1 staged

    // ---- chunks 1..15 ----
    for (int kc = 1; kc < NCHUNK; ++kc) {
        if (kc < NCHUNK - 1) STAGE(kc + 1);
        const unsigned short* fb = &cbuf[(kc & 1) * CHUNK_USH];
        #pragma unroll
        for (int nt2 = 0; nt2 < 2; ++nt2) {
            int nt = 2 * h + nt2;
            SCORE_NT(fb, kc, nt);
            COLLECT(kc * 64 + nt * 16);
        }
        SHARE_MINS();
        __syncthreads();
    }

    // ---- refine: lane-parallel fp64 exact rescore, atomicMin packed key ----
    auto refine_pair = [&](int row, int code) {
        const float* rrow = rsrc + (size_t)(rows0 + row) * DIM;
        const float* crow = cbf + (size_t)code * DIM;
        double dd0 = 0.0, dd1 = 0.0, dd2 = 0.0, dd3 = 0.0;
        #pragma unroll 2
        for (int d = 0; d < DIM; d += 16) {
            float4 c0 = *(const float4*)(crow + d);
            float4 c1 = *(const float4*)(crow + d + 4);
            float4 c2 = *(const float4*)(crow + d + 8);
            float4 c3 = *(const float4*)(crow + d + 12);
            float4 r0 = *(const float4*)(rrow + d);
            float4 r1 = *(const float4*)(rrow + d + 4);
            float4 r2 = *(const float4*)(rrow + d + 8);
            float4 r3 = *(const float4*)(rrow + d + 12);
            dd0 = fma((double)c0.x, (double)r0.x, dd0);
            dd0 = fma((double)c0.y, (double)r0.y, dd0);
            dd0 = fma((double)c0.z, (double)r0.z, dd0);
            dd0 = fma((double)c0.w, (double)r0.w, dd0);
            dd1 = fma((double)c1.x, (double)r1.x, dd1);
            dd1 = fma((double)c1.y, (double)r1.y, dd1);
            dd1 = fma((double)c1.z, (double)r1.z, dd1);
            dd1 = fma((double)c1.w, (double)r1.w, dd1);
            dd2 = fma((double)c2.x, (double)r2.x, dd2);
            dd2 = fma((double)c2.y, (double)r2.y, dd2);
            dd2 = fma((double)c2.z, (double)r2.z, dd2);
            dd2 = fma((double)c2.w, (double)r2.w, dd2);
            dd3 = fma((double)c3.x, (double)r3.x, dd3);
            dd3 = fma((double)c3.y, (double)r3.y, dd3);
            dd3 = fma((double)c3.z, (double)r3.z, dd3);
            dd3 = fma((double)c3.w, (double)r3.w, dd3);
        }
        double s = cn2dL[code] - 2.0 * ((dd0 + dd1) + (dd2 + dd3));
        long long xb = __double_as_longlong(s);
        unsigned long long o = (xb < 0) ? (unsigned long long)(~xb)
                                        : ((unsigned long long)xb | 0x8000000000000000ULL);
        atomicMin(&winkey[row], (o & ~1023ULL) | (unsigned long long)code);
    };

    for (int p = tid; p < BM * CAP; p += 512) {
        int row = p >> 5, slot = p & (CAP - 1);
        int c = cnt[row];
        if (c <= CAP && slot < c) refine_pair(row, (int)cand[row * CAP + slot]);
    }
    for (int row = 0; row < BM; ++row) {        // sound fallback, ~never taken
        if (cnt[row] > CAP)
            for (int code = tid; code < KCODES; code += 512) refine_pair(row, code);
    }
    __syncthreads();
    if (tid < BM) {
        int best = (int)(winkey[tid] & 1023ULL);
        winid[tid] = best;
        ids_out[(size_t)(rows0 + tid) * LEVELS + level] = (float)best;
    }
    __syncthreads();

    // ---- epilogue: gather q, zq[l] = zq[l-1] + (r + (q-r)), r' = r - q, loss ----
    float lacc = 0.f;
    #pragma unroll 4
    for (int it = 0; it < 16; ++it) {
        int rowloc = it * 8 + w;
        int grow = rows0 + rowloc;
        int d0 = l * 4;
        int code = winid[rowloc];
        float4 q = *(const float4*)(cbf + (size_t)code * DIM + d0);
        float4 r = *(const float4*)(rsrc + (size_t)grow * DIM + d0);
        float4 zp = {0.f, 0.f, 0.f, 0.f};
        if (zqprev) zp = *(const float4*)(zqprev + (size_t)grow * DIM + d0);
        float dx = q.x - r.x, dy = q.y - r.y, dz = q.z - r.z, dw = q.w - r.w;
        float4 zo;
        zo.x = zp.x + (r.x + dx); zo.y = zp.y + (r.y + dy);
        zo.z = zp.z + (r.z + dz); zo.w = zp.w + (r.w + dw);
        *(float4*)(zqout + (size_t)grow * DIM + d0) = zo;
        if (rnext) {
            float4 rn; rn.x = -dx; rn.y = -dy; rn.z = -dz; rn.w = -dw;
            *(float4*)(rnext + (size_t)grow * DIM + d0) = rn;
        }
        lacc += dx * dx + dy * dy + dz * dz + dw * dw;
    }
    #pragma unroll
    for (int m = 32; m; m >>= 1) lacc += __shfl_xor(lacc, m);
    if (l == 0) wl[w] = lacc;
    __syncthreads();
    if (tid == 0) {
        float t = 0.f;
        #pragma unroll
        for (int i = 0; i < 8; ++i) t += wl[i];
        blockpart[level * (NROWS / BM) + blockIdx.x] = (double)t;
    }
}

// ---- k_loss: deterministic fixed-order reduction of block partials ----
__global__ __launch_bounds__(256) void k_loss(const double* __restrict__ part,
                                              float* __restrict__ loss) {
    __shared__ double sd[256];
    int tid = threadIdx.x;
    double a = 0.0;
    #pragma unroll
    for (int i = 0; i < 8; ++i) a += part[i * 256 + tid];   // 2048 entries
    sd[tid] = a; __syncthreads();
    for (int s = 128; s > 0; s >>= 1) {
        if (tid < s) sd[tid] += sd[tid + s];
        __syncthreads();
    }
    if (tid == 0) *loss = (float)(sd[0] * (1.25 / 16777216.0));
}

extern "C" void kernel_launch(void* const* d_in, const int* in_sizes, int n_in,
                              void* d_out, int out_size, void* d_ws, size_t ws_size,
                              hipStream_t stream) {
    const float* data = (const float*)d_in[0];
    const float* cb   = (const float*)d_in[1];
    float* out  = (float*)d_out;
    float* zq   = out;
    float* ids  = out + IDS_OFF;
    float* loss = out + IDS_OFF + NROWS * LEVELS;
    char* ws = (char*)d_ws;
    unsigned short* cbw = (unsigned short*)ws;                 // 2 MB frag-tiled bf16
    float*  cn2w  = (float*)(ws + (size_t)LEVELS * LVL_USH * 2);           // 16 KB
    double* cn2d  = (double*)(ws + (size_t)LEVELS * LVL_USH * 2 + 16384);  // 32 KB
    double* bpart = (double*)(ws + (size_t)LEVELS * LVL_USH * 2 + 16384 + 32768); // 16 KB
    float* rscr = zq + (size_t)3 * CH;   // zq_stack[3] slot doubles as residual scratch

    k_prep<<<LEVELS * KCODES, 64, 0, stream>>>(cb, cbw, cn2w, cn2d);
    for (int lv = 0; lv < LEVELS; ++lv) {
        const float* rsrc   = (lv == 0) ? data : rscr;
        const float* zqprev = (lv == 0) ? nullptr : zq + (size_t)(lv - 1) * CH;
        float* zqout = zq + (size_t)lv * CH;
        float* rnext = (lv == 3) ? nullptr : rscr;
        k_score<<<NROWS / BM, 512, 0, stream>>>(
            rsrc, cb + (size_t)lv * KCODES * DIM, cbw + (size_t)lv * LVL_USH,
            cn2w + (size_t)lv * KCODES, cn2d + (size_t)lv * KCODES,
            zqprev, zqout, rnext, ids, bpart, lv);
    }
    k_loss<<<1, 256, 0, stream>>>(bpart, loss);
}

// Round 4
// 1057.498 us; speedup vs baseline: 1.4356x; 1.4356x over previous
//
#include <hip/hip_runtime.h>
#include <hip/hip_bf16.h>

// RQ-VAE residual quantization, MI355X gfx950.
// data [65536][256] f32, codebooks [4][1024][256] f32.
// out = [zq_stack 4*65536*256][semantic_ids 65536*4 (as float)][loss 1], all f32.
//
// Single-pass bf16-MFMA scores: per chunk, scores are buffered in registers,
// the per-row running min is reduced across lanes INCLUDING the current
// chunk, then candidates within MARGIN of that min are collected (superset
// of the final margin set). fp64 exact rescore of candidates (atomicMin on
// packed score|code key, lowest-index tie-break), fused gather/update
// epilogue. 256-thread blocks: 4 waves, each owning 32 rows x all 64 codes
// of a chunk. Residual r lives in the zq_stack[3] slot of d_out
// (read-before-write per thread at level 3).

#define NROWS   65536
#define DIM     256
#define KCODES  1024
#define LEVELS  4
#define CH      (NROWS * DIM)
#define IDS_OFF (LEVELS * CH)

#define BM      128
#define NCHUNK  16
#define CAP     32
#define MARGIN  8.0f
#define CHUNK_USH 16384          // 64 codes * 256 bf16
#define LVL_USH   262144         // 1024 * 256

typedef __attribute__((ext_vector_type(8))) short bf16x8;
typedef __attribute__((ext_vector_type(4))) float f32x4;
typedef const __attribute__((address_space(1))) void* gp_t;
typedef __attribute__((address_space(3))) void* lp_t;

__device__ __forceinline__ unsigned short f2bf(float x) {
    __hip_bfloat16 h = __float2bfloat16(x);
    unsigned short r; __builtin_memcpy(&r, &h, 2); return r;
}
__device__ __forceinline__ float bf2f(unsigned short u) {
    __hip_bfloat16 h; __builtin_memcpy(&h, &u, 2); return __bfloat162float(h);
}

// ---- k_prep: frag-tiled bf16 codebook + fp32 sum(c_bf16^2) + fp64 sum(c^2) ----
// Layout (ushort idx): ((((L*16+chunk)*4+nt)*8+kk)*64 + (g*16+li))*8 + h
__global__ __launch_bounds__(64) void k_prep(const float* __restrict__ cb,
                                             unsigned short* __restrict__ cbw,
                                             float* __restrict__ cn2w,
                                             double* __restrict__ cn2d) {
    int cr = blockIdx.x;                 // level*1024 + code
    int L = cr >> 10, c = cr & 1023;
    int l = threadIdx.x;                 // handles floats l*4..l*4+3
    float4 v = *(const float4*)(cb + (size_t)cr * DIM + l * 4);
    ushort4 st;
    st.x = f2bf(v.x); st.y = f2bf(v.y); st.z = f2bf(v.z); st.w = f2bf(v.w);
    int b = l * 8;
    int kk = b >> 6, g = (b >> 4) & 3, h = (b & 15) >> 1;
    int idx = ((((L * 16 + (c >> 6)) * 4 + ((c >> 4) & 3)) * 8 + kk) * 64
               + (g * 16 + (c & 15))) * 8 + h;
    *(ushort4*)(cbw + idx) = st;
    float f0 = bf2f(st.x), f1 = bf2f(st.y), f2 = bf2f(st.z), f3 = bf2f(st.w);
    float sq = f0 * f0 + f1 * f1 + f2 * f2 + f3 * f3;
    double dq = (double)v.x * v.x + (double)v.y * v.y
              + (double)v.z * v.z + (double)v.w * v.w;
    #pragma unroll
    for (int m = 32; m; m >>= 1) {
        sq += __shfl_xor(sq, m);
        dq += __shfl_xor(dq, m);
    }
    if (l == 0) { cn2w[cr] = sq; cn2d[cr] = dq; }
}

// ---- k_score: single-pass approx scores + exact refine + update ----
__global__ __launch_bounds__(256) void k_score(
    const float* rsrc,
    const float* __restrict__ cbf,
    const unsigned short* __restrict__ cbwL,
    const float* __restrict__ cn2L,
    const double* __restrict__ cn2dL,
    const float* zqprev, float* zqout, float* rnext,
    float* __restrict__ ids_out,
    double* __restrict__ blockpart,
    int level)
{
    __shared__ unsigned short cbuf[2 * CHUNK_USH];   // 64 KB double buffer
    __shared__ float cn2s[KCODES];                   // 4 KB
    __shared__ unsigned short cand[BM * CAP];        // 8 KB
    __shared__ int cnt[BM];
    __shared__ unsigned long long winkey[BM];
    __shared__ int winid[BM];
    __shared__ float wl[4];

    const int tid = threadIdx.x;
    const int w = tid >> 6, l = tid & 63;
    const int g = l >> 4, li = l & 15;
    const int rows0 = blockIdx.x * BM;

    // stage chunk T into buffer T&1 (linear DMA: 8 x 1KB per wave)
    #define STAGE(T) do {                                                      \
        int _kc = (T) & 15, _bs = (T) & 1;                                     \
        const unsigned short* _g = cbwL + _kc * CHUNK_USH + (w * 8) * 512;     \
        unsigned short* _d = &cbuf[_bs * CHUNK_USH + (w * 8) * 512];           \
        _Pragma("unroll")                                                      \
        for (int _r = 0; _r < 8; ++_r)                                         \
            __builtin_amdgcn_global_load_lds((gp_t)(_g + _r * 512 + l * 8),    \
                                             (lp_t)(_d + _r * 512), 16, 0, 0); \
    } while (0)

    STAGE(0);
    cn2s[tid]       = cn2L[tid];
    cn2s[tid + 256] = cn2L[tid + 256];
    cn2s[tid + 512] = cn2L[tid + 512];
    cn2s[tid + 768] = cn2L[tid + 768];
    if (tid < BM) { cnt[tid] = 0; winkey[tid] = ~0ULL; }

    // A-fragments: 32 rows per wave in bf16 registers (reused all chunks)
    bf16x8 af[2][8];
    #pragma unroll
    for (int mi = 0; mi < 2; ++mi) {
        int row = rows0 + (2 * w + mi) * 16 + li;
        const float* rp = rsrc + (size_t)row * DIM;
        #pragma unroll
        for (int kk = 0; kk < 8; ++kk) {
            int d0 = kk * 32 + 8 * g;
            float4 v0 = *(const float4*)(rp + d0);
            float4 v1 = *(const float4*)(rp + d0 + 4);
            bf16x8 t;
            t[0] = (short)f2bf(v0.x); t[1] = (short)f2bf(v0.y);
            t[2] = (short)f2bf(v0.z); t[3] = (short)f2bf(v0.w);
            t[4] = (short)f2bf(v1.x); t[5] = (short)f2bf(v1.y);
            t[6] = (short)f2bf(v1.z); t[7] = (short)f2bf(v1.w);
            af[mi][kk] = t;
        }
    }

    float minv[2][4];
    float sbuf[4][2][4];                 // [nt][mi][rg] current chunk's scores
    #pragma unroll
    for (int mi = 0; mi < 2; ++mi)
        #pragma unroll
        for (int rg = 0; rg < 4; ++rg) minv[mi][rg] = 3.0e38f;

    __syncthreads();                      // chunk 0 staged; cn2s/cnt ready

    for (int kc = 0; kc < NCHUNK; ++kc) {
        if (kc < NCHUNK - 1) STAGE(kc + 1);     // next chunk under compute
        const unsigned short* fb = &cbuf[(kc & 1) * CHUNK_USH];

        // score all 4 nt-tiles into sbuf, update private running min
        #pragma unroll
        for (int nt = 0; nt < 4; ++nt) {
            f32x4 acc0 = {0.f, 0.f, 0.f, 0.f};
            f32x4 acc1 = {0.f, 0.f, 0.f, 0.f};
            const unsigned short* fp8 = fb + (nt * 8) * 512 + l * 8;
            #pragma unroll
            for (int kk = 0; kk < 8; ++kk) {
                bf16x8 bfr = *(const bf16x8*)(fp8 + kk * 512);
                acc0 = __builtin_amdgcn_mfma_f32_16x16x32_bf16(af[0][kk], bfr, acc0, 0, 0, 0);
                acc1 = __builtin_amdgcn_mfma_f32_16x16x32_bf16(af[1][kk], bfr, acc1, 0, 0, 0);
            }
            float c2 = cn2s[kc * 64 + nt * 16 + li];
            #pragma unroll
            for (int rg = 0; rg < 4; ++rg) {
                float v0 = __builtin_fmaf(-2.f, acc0[rg], c2);
                float v1 = __builtin_fmaf(-2.f, acc1[rg], c2);
                sbuf[nt][0][rg] = v0;
                sbuf[nt][1][rg] = v1;
                minv[0][rg] = fminf(minv[0][rg], v0);
                minv[1][rg] = fminf(minv[1][rg], v1);
            }
        }

        // cross-lane running min (includes current chunk) -> fresh threshold
        float rowm[2][4];
        #pragma unroll
        for (int mi = 0; mi < 2; ++mi)
            #pragma unroll
            for (int rg = 0; rg < 4; ++rg) {
                float v = minv[mi][rg];
                v = fminf(v, __shfl_xor(v, 1));
                v = fminf(v, __shfl_xor(v, 2));
                v = fminf(v, __shfl_xor(v, 4));
                v = fminf(v, __shfl_xor(v, 8));
                minv[mi][rg] = v;
                rowm[mi][rg] = v + MARGIN;
            }

        // collect candidates from this chunk with the post-chunk threshold
        #pragma unroll
        for (int nt = 0; nt < 4; ++nt) {
            bool any = false;
            #pragma unroll
            for (int mi = 0; mi < 2; ++mi)
                #pragma unroll
                for (int rg = 0; rg < 4; ++rg)
                    any |= (sbuf[nt][mi][rg] < rowm[mi][rg]);
            if (__any(any)) {
                #pragma unroll
                for (int mi = 0; mi < 2; ++mi)
                    #pragma unroll
                    for (int rg = 0; rg < 4; ++rg)
                        if (sbuf[nt][mi][rg] < rowm[mi][rg]) {
                            int row = (2 * w + mi) * 16 + 4 * g + rg;
                            int slot = atomicAdd(&cnt[row], 1);
                            if (slot < CAP)
                                cand[row * CAP + slot] =
                                    (unsigned short)(kc * 64 + nt * 16 + li);
                        }
            }
        }
        __syncthreads();   // chunk kc reads done + chunk kc+1 staged
    }

    // ---- refine: lane-parallel fp64 exact rescore, atomicMin packed key ----
    auto refine_pair = [&](int row, int code) {
        const float* rrow = rsrc + (size_t)(rows0 + row) * DIM;
        const float* crow = cbf + (size_t)code * DIM;
        double dd0 = 0.0, dd1 = 0.0, dd2 = 0.0, dd3 = 0.0;
        #pragma unroll 2
        for (int d = 0; d < DIM; d += 16) {
            float4 c0 = *(const float4*)(crow + d);
            float4 c1 = *(const float4*)(crow + d + 4);
            float4 c2 = *(const float4*)(crow + d + 8);
            float4 c3 = *(const float4*)(crow + d + 12);
            float4 r0 = *(const float4*)(rrow + d);
            float4 r1 = *(const float4*)(rrow + d + 4);
            float4 r2 = *(const float4*)(rrow + d + 8);
            float4 r3 = *(const float4*)(rrow + d + 12);
            dd0 = fma((double)c0.x, (double)r0.x, dd0);
            dd0 = fma((double)c0.y, (double)r0.y, dd0);
            dd0 = fma((double)c0.z, (double)r0.z, dd0);
            dd0 = fma((double)c0.w, (double)r0.w, dd0);
            dd1 = fma((double)c1.x, (double)r1.x, dd1);
            dd1 = fma((double)c1.y, (double)r1.y, dd1);
            dd1 = fma((double)c1.z, (double)r1.z, dd1);
            dd1 = fma((double)c1.w, (double)r1.w, dd1);
            dd2 = fma((double)c2.x, (double)r2.x, dd2);
            dd2 = fma((double)c2.y, (double)r2.y, dd2);
            dd2 = fma((double)c2.z, (double)r2.z, dd2);
            dd2 = fma((double)c2.w, (double)r2.w, dd2);
            dd3 = fma((double)c3.x, (double)r3.x, dd3);
            dd3 = fma((double)c3.y, (double)r3.y, dd3);
            dd3 = fma((double)c3.z, (double)r3.z, dd3);
            dd3 = fma((double)c3.w, (double)r3.w, dd3);
        }
        double s = cn2dL[code] - 2.0 * ((dd0 + dd1) + (dd2 + dd3));
        long long xb = __double_as_longlong(s);
        unsigned long long o = (xb < 0) ? (unsigned long long)(~xb)
                                        : ((unsigned long long)xb | 0x8000000000000000ULL);
        atomicMin(&winkey[row], (o & ~1023ULL) | (unsigned long long)code);
    };

    for (int p = tid; p < BM * CAP; p += 256) {
        int row = p >> 5, slot = p & (CAP - 1);
        int c = cnt[row];
        if (c <= CAP && slot < c) refine_pair(row, (int)cand[row * CAP + slot]);
    }
    for (int row = 0; row < BM; ++row) {        // sound fallback, ~never taken
        if (cnt[row] > CAP)
            for (int code = tid; code < KCODES; code += 256) refine_pair(row, code);
    }
    __syncthreads();
    if (tid < BM) {
        int best = (int)(winkey[tid] & 1023ULL);
        winid[tid] = best;
        ids_out[(size_t)(rows0 + tid) * LEVELS + level] = (float)best;
    }
    __syncthreads();

    // ---- epilogue: gather q, zq[l] = zq[l-1] + (r + (q-r)), r' = r - q, loss ----
    float lacc = 0.f;
    for (int it = 0; it < 32; ++it) {
        int rowloc = it * 4 + w;
        int grow = rows0 + rowloc;
        int d0 = l * 4;
        int code = winid[rowloc];
        float4 q = *(const float4*)(cbf + (size_t)code * DIM + d0);
        float4 r = *(const float4*)(rsrc + (size_t)grow * DIM + d0);
        float4 zp = {0.f, 0.f, 0.f, 0.f};
        if (zqprev) zp = *(const float4*)(zqprev + (size_t)grow * DIM + d0);
        float dx = q.x - r.x, dy = q.y - r.y, dz = q.z - r.z, dw = q.w - r.w;
        float4 zo;
        zo.x = zp.x + (r.x + dx); zo.y = zp.y + (r.y + dy);
        zo.z = zp.z + (r.z + dz); zo.w = zp.w + (r.w + dw);
        *(float4*)(zqout + (size_t)grow * DIM + d0) = zo;
        if (rnext) {
            float4 rn; rn.x = -dx; rn.y = -dy; rn.z = -dz; rn.w = -dw;
            *(float4*)(rnext + (size_t)grow * DIM + d0) = rn;
        }
        lacc += dx * dx + dy * dy + dz * dz + dw * dw;
    }
    #pragma unroll
    for (int m = 32; m; m >>= 1) lacc += __shfl_xor(lacc, m);
    if (l == 0) wl[w] = lacc;
    __syncthreads();
    if (tid == 0)
        blockpart[level * (NROWS / BM) + blockIdx.x] =
            (double)wl[0] + (double)wl[1] + (double)wl[2] + (double)wl[3];
}

// ---- k_loss: deterministic fixed-order reduction of block partials ----
__global__ __launch_bounds__(256) void k_loss(const double* __restrict__ part,
                                              float* __restrict__ loss) {
    __shared__ double sd[256];
    int tid = threadIdx.x;
    double a = 0.0;
    #pragma unroll
    for (int i = 0; i < 8; ++i) a += part[i * 256 + tid];   // 2048 entries
    sd[tid] = a; __syncthreads();
    for (int s = 128; s > 0; s >>= 1) {
        if (tid < s) sd[tid] += sd[tid + s];
        __syncthreads();
    }
    if (tid == 0) *loss = (float)(sd[0] * (1.25 / 16777216.0));
}

extern "C" void kernel_launch(void* const* d_in, const int* in_sizes, int n_in,
                              void* d_out, int out_size, void* d_ws, size_t ws_size,
                              hipStream_t stream) {
    const float* data = (const float*)d_in[0];
    const float* cb   = (const float*)d_in[1];
    float* out  = (float*)d_out;
    float* zq   = out;
    float* ids  = out + IDS_OFF;
    float* loss = out + IDS_OFF + NROWS * LEVELS;
    char* ws = (char*)d_ws;
    unsigned short* cbw = (unsigned short*)ws;                 // 2 MB frag-tiled bf16
    float*  cn2w  = (float*)(ws + (size_t)LEVELS * LVL_USH * 2);           // 16 KB
    double* cn2d  = (double*)(ws + (size_t)LEVELS * LVL_USH * 2 + 16384);  // 32 KB
    double* bpart = (double*)(ws + (size_t)LEVELS * LVL_USH * 2 + 16384 + 32768); // 16 KB
    float* rscr = zq + (size_t)3 * CH;   // zq_stack[3] slot doubles as residual scratch

    k_prep<<<LEVELS * KCODES, 64, 0, stream>>>(cb, cbw, cn2w, cn2d);
    for (int lv = 0; lv < LEVELS; ++lv) {
        const float* rsrc   = (lv == 0) ? data : rscr;
        const float* zqprev = (lv == 0) ? nullptr : zq + (size_t)(lv - 1) * CH;
        float* zqout = zq + (size_t)lv * CH;
        float* rnext = (lv == 3) ? nullptr : rscr;
        k_score<<<NROWS / BM, 256, 0, stream>>>(
            rsrc, cb + (size_t)lv * KCODES * DIM, cbw + (size_t)lv * LVL_USH,
            cn2w + (size_t)lv * KCODES, cn2d + (size_t)lv * KCODES,
            zqprev, zqout, rnext, ids, bpart, lv);
    }
    k_loss<<<1, 256, 0, stream>>>(bpart, loss);
}